// Round 1
// baseline (353.109 us; speedup 1.0000x reference)
//
#include <hip/hip_runtime.h>

#define TT 4096
#define CC 1024
#define DD 128

typedef __attribute__((ext_vector_type(8))) short s16x8;
typedef __attribute__((ext_vector_type(4))) short s16x4;
typedef __attribute__((ext_vector_type(8))) __bf16 bf16x8;
typedef __attribute__((ext_vector_type(4))) float f32x4;

__device__ __forceinline__ short f2bf(float f) {
    union { float f; unsigned u; } v; v.f = f;
    unsigned r = v.u + 0x7fffu + ((v.u >> 16) & 1u);
    return (short)(r >> 16);
}

__device__ __forceinline__ f32x4 mfma16(s16x8 a, s16x8 b, f32x4 c) {
    return __builtin_amdgcn_mfma_f32_16x16x32_bf16(
        __builtin_bit_cast(bf16x8, a), __builtin_bit_cast(bf16x8, b), c, 0, 0, 0);
}

// ---------------- kernel 0: transpose weights -> wT bf16 [3][D][C], scale wq ----
__global__ void wt_kernel(const float* __restrict__ wq, const float* __restrict__ wk,
                          const float* __restrict__ wv, short* __restrict__ wT) {
    int idx = blockIdx.x * 256 + threadIdx.x;   // 3*128*1024 = 393216 threads
    int d = idx & 127;
    int c = (idx >> 7) & 1023;
    int wsel = idx >> 17;
    const float* w = (wsel == 0) ? wq : (wsel == 1) ? wk : wv;
    float v = w[(size_t)c * DD + d];
    if (wsel == 0) v *= 0.08838834764831845f;   // D^-0.5 folded into Q
    wT[(size_t)wsel * DD * CC + (size_t)d * CC + c] = f2bf(v);
}

// ---------------- kernel 1: QKV projection GEMM --------------------------------
// grid (256, 3): M-tile (128 rows of x), weight select. 4 waves, BM=128 BN=128 BK=64.
__global__ __launch_bounds__(256)
void qkv_kernel(const float* __restrict__ x, const short* __restrict__ wT,
                short* __restrict__ qo, short* __restrict__ ko, short* __restrict__ vTo) {
    __shared__ short lx[8192];  // [128][64] bf16, XOR-swizzled
    __shared__ short lw[8192];  // [128 n][64 k] bf16 (wT rows), XOR-swizzled
    const int mt = blockIdx.x;
    const int wsel = blockIdx.y;
    const int tid = threadIdx.x;
    const int lane = tid & 63;
    const int wid = tid >> 6;
    const int l15 = lane & 15, g = lane >> 4;
    const short* wb = wT + (size_t)wsel * DD * CC;

    const f32x4 fz = {0.f, 0.f, 0.f, 0.f};
    f32x4 acc[2][8];
#pragma unroll
    for (int mr = 0; mr < 2; mr++)
#pragma unroll
        for (int nr = 0; nr < 8; nr++) acc[mr][nr] = fz;

    for (int kc = 0; kc < CC / 64; kc++) {
        __syncthreads();
        // stage x tile [128][64] fp32 -> bf16 LDS (convert in regs; 8 float4/thread)
#pragma unroll
        for (int j = 0; j < 8; j++) {
            int f = j * 256 + tid;
            int row = f >> 4, c4 = f & 15;
            float4 xv = *(const float4*)(x + (size_t)(mt * 128 + row) * CC + kc * 64 + c4 * 4);
            s16x4 s4;
            s4[0] = f2bf(xv.x); s4[1] = f2bf(xv.y); s4[2] = f2bf(xv.z); s4[3] = f2bf(xv.w);
            int byte = (row * 128 + c4 * 8) ^ ((row & 7) << 4);
            *(s16x4*)((char*)lx + byte) = s4;
        }
        // stage wT tile [128][64] bf16
#pragma unroll
        for (int j = 0; j < 8; j++) {
            int f = j * 256 + tid;
            int row = f >> 4, c4 = f & 15;
            s16x4 s4 = *(const s16x4*)(wb + (size_t)row * CC + kc * 64 + c4 * 4);
            int byte = (row * 128 + c4 * 8) ^ ((row & 7) << 4);
            *(s16x4*)((char*)lw + byte) = s4;
        }
        __syncthreads();
#pragma unroll
        for (int ks = 0; ks < 2; ks++) {
            s16x8 af[2];
#pragma unroll
            for (int mr = 0; mr < 2; mr++) {
                int row = wid * 32 + mr * 16 + l15;
                int byte = (row * 128 + ks * 64 + g * 16) ^ ((row & 7) << 4);
                af[mr] = *(const s16x8*)((const char*)lx + byte);
            }
#pragma unroll
            for (int nr = 0; nr < 8; nr++) {
                int row = nr * 16 + l15;
                int byte = (row * 128 + ks * 64 + g * 16) ^ ((row & 7) << 4);
                s16x8 bfg = *(const s16x8*)((const char*)lw + byte);
#pragma unroll
                for (int mr = 0; mr < 2; mr++)
                    acc[mr][nr] = mfma16(af[mr], bfg, acc[mr][nr]);
            }
        }
    }
    // store: C/D layout row = 4*(lane>>4)+i, col = lane&15  [m89-verified]
    const int bidx = mt >> 5;           // batch (T/BM = 32 tiles per batch)
    const int t0 = (mt & 31) * 128;
#pragma unroll
    for (int mr = 0; mr < 2; mr++)
#pragma unroll
        for (int nr = 0; nr < 8; nr++)
#pragma unroll
            for (int i = 0; i < 4; i++) {
                int t = t0 + wid * 32 + mr * 16 + g * 4 + i;
                int d = nr * 16 + l15;
                short val = f2bf(acc[mr][nr][i]);
                if (wsel == 0)      qo[((size_t)bidx * TT + t) * DD + d] = val;
                else if (wsel == 1) ko[((size_t)bidx * TT + t) * DD + d] = val;
                else                vTo[((size_t)bidx * DD + d) * TT + t] = val;  // V^T
            }
}

// ---------------- kernel 2: causal flash attention ------------------------------
// grid (64, 8) = (q-tile, batch). 4 waves x 16 q-rows, KVBLK=64, D=128.
__global__ __launch_bounds__(256)
void attn_kernel(const short* __restrict__ qb, const short* __restrict__ kb,
                 const short* __restrict__ vb, float* __restrict__ out) {
    __shared__ short lk[8192];  // K tile [64][128] bf16, swizzled
    __shared__ short lv[8192];  // V^T tile [128][64] bf16, swizzled
    __shared__ short lp[4096];  // P per wave [16][64] bf16, swizzled
    const int qt = blockIdx.x, b = blockIdx.y;
    const int tid = threadIdx.x, lane = tid & 63, wid = tid >> 6;
    const int l15 = lane & 15, g = lane >> 4;
    const int qbase = qt * 64;
    const int wq0 = qbase + wid * 16;

    // hoist Q fragments (pre-scaled by D^-0.5 at projection time)
    s16x8 qf[4];
    {
        const short* qp = qb + ((size_t)b * TT + wq0 + l15) * DD + g * 8;
#pragma unroll
        for (int ks = 0; ks < 4; ks++) qf[ks] = *(const s16x8*)(qp + ks * 32);
    }
    const f32x4 fz = {0.f, 0.f, 0.f, 0.f};
    f32x4 o[8];
#pragma unroll
    for (int n = 0; n < 8; n++) o[n] = fz;
    float rmax[4] = {-1e30f, -1e30f, -1e30f, -1e30f};
    float rsum[4] = {0.f, 0.f, 0.f, 0.f};

    for (int kvt = 0; kvt <= qt; kvt++) {
        const int kv0 = kvt * 64;
        __syncthreads();
        // stage K tile (4 x short8 per thread)
#pragma unroll
        for (int j = 0; j < 4; j++) {
            int ci = j * 256 + tid;
            int r = ci >> 4, c8 = ci & 15;
            s16x8 t8 = *(const s16x8*)(kb + ((size_t)b * TT + kv0 + r) * DD + c8 * 8);
            int byte = (r * 256 + c8 * 16) ^ ((r & 7) << 4);
            *(s16x8*)((char*)lk + byte) = t8;
        }
        // stage V^T tile
#pragma unroll
        for (int j = 0; j < 4; j++) {
            int ci = j * 256 + tid;
            int d = ci >> 3, c8 = ci & 7;
            s16x8 t8 = *(const s16x8*)(vb + ((size_t)b * DD + d) * TT + kv0 + c8 * 8);
            int byte = (d * 128 + c8 * 16) ^ ((d & 7) << 4);
            *(s16x8*)((char*)lv + byte) = t8;
        }
        __syncthreads();
        if (kv0 > wq0 + 15) continue;   // wave entirely above-diagonal for this tile

        // S = Q K^T   (4 col-subtiles x 4 d-steps)
        f32x4 s[4];
#pragma unroll
        for (int sub = 0; sub < 4; sub++) {
            f32x4 a = fz;
#pragma unroll
            for (int ks = 0; ks < 4; ks++) {
                int row = sub * 16 + l15;
                int byte = (row * 256 + ks * 64 + g * 16) ^ ((row & 7) << 4);
                s16x8 kf = *(const s16x8*)((const char*)lk + byte);
                a = mfma16(qf[ks], kf, a);
            }
            s[sub] = a;
        }
        // causal mask (only near the diagonal)
        if (kv0 + 63 > wq0) {
#pragma unroll
            for (int sub = 0; sub < 4; sub++)
#pragma unroll
                for (int i = 0; i < 4; i++) {
                    int col = kv0 + sub * 16 + l15;
                    int row = wq0 + g * 4 + i;
                    if (col > row) s[sub][i] = -1e30f;
                }
        }
        // online softmax: wave-parallel row reduce (rows live in 16-lane groups)
        float mnew[4], scal[4];
#pragma unroll
        for (int i = 0; i < 4; i++) {
            float m0 = fmaxf(fmaxf(s[0][i], s[1][i]), fmaxf(s[2][i], s[3][i]));
            m0 = fmaxf(m0, __shfl_xor(m0, 1));
            m0 = fmaxf(m0, __shfl_xor(m0, 2));
            m0 = fmaxf(m0, __shfl_xor(m0, 4));
            m0 = fmaxf(m0, __shfl_xor(m0, 8));
            mnew[i] = fmaxf(rmax[i], m0);
            scal[i] = __expf(rmax[i] - mnew[i]);
            rmax[i] = mnew[i];
        }
        float ls[4] = {0.f, 0.f, 0.f, 0.f};
#pragma unroll
        for (int sub = 0; sub < 4; sub++)
#pragma unroll
            for (int i = 0; i < 4; i++) {
                float p = __expf(s[sub][i] - mnew[i]);
                ls[i] += p;
                int prow = g * 4 + i;
                int byte = (wid * 2048 + prow * 128 + (sub * 16 + l15) * 2) ^ ((prow & 7) << 4);
                *(short*)((char*)lp + byte) = f2bf(p);
            }
#pragma unroll
        for (int i = 0; i < 4; i++) {
            float t = ls[i];
            t += __shfl_xor(t, 1);
            t += __shfl_xor(t, 2);
            t += __shfl_xor(t, 4);
            t += __shfl_xor(t, 8);
            rsum[i] = rsum[i] * scal[i] + t;
        }
#pragma unroll
        for (int n = 0; n < 8; n++)
#pragma unroll
            for (int i = 0; i < 4; i++) o[n][i] *= scal[i];
        // PV: A = P (LDS round-trip gives A-layout), B = V^T rows (contig-8 k)
#pragma unroll
        for (int ks2 = 0; ks2 < 2; ks2++) {
            int pbyte = (wid * 2048 + l15 * 128 + ks2 * 64 + g * 16) ^ ((l15 & 7) << 4);
            s16x8 pf = *(const s16x8*)((const char*)lp + pbyte);
#pragma unroll
            for (int n = 0; n < 8; n++) {
                int vrow = n * 16 + l15;
                int vbyte = (vrow * 128 + ks2 * 64 + g * 16) ^ ((vrow & 7) << 4);
                s16x8 vf = *(const s16x8*)((const char*)lv + vbyte);
                o[n] = mfma16(pf, vf, o[n]);
            }
        }
    }
    float inv[4];
#pragma unroll
    for (int i = 0; i < 4; i++) inv[i] = 1.0f / rsum[i];
#pragma unroll
    for (int n = 0; n < 8; n++)
#pragma unroll
        for (int i = 0; i < 4; i++) {
            int row = wq0 + g * 4 + i;
            int d = n * 16 + l15;
            out[((size_t)b * TT + row) * DD + d] = o[n][i] * inv[i];
        }
}

// ---------------- launch ---------------------------------------------------------
extern "C" void kernel_launch(void* const* d_in, const int* in_sizes, int n_in,
                              void* d_out, int out_size, void* d_ws, size_t ws_size,
                              hipStream_t stream) {
    const float* x  = (const float*)d_in[0];
    const float* wq = (const float*)d_in[1];
    const float* wk = (const float*)d_in[2];
    const float* wv = (const float*)d_in[3];
    float* out = (float*)d_out;
    char* ws = (char*)d_ws;
    // ws layout: wT bf16 [3][128][1024] (768 KB) | q bf16 [8][4096][128] (8MB)
    //            | k bf16 (8MB) | vT bf16 [8][128][4096] (8MB)  => ~24.8 MB total
    short* wT = (short*)ws;
    short* qb = (short*)(ws + 786432);
    short* kb = (short*)(ws + 786432 + 8388608);
    short* vb = (short*)(ws + 786432 + 16777216);

    wt_kernel<<<1536, 256, 0, stream>>>(wq, wk, wv, wT);
    qkv_kernel<<<dim3(256, 3), 256, 0, stream>>>(x, wT, qb, kb, vb);
    attn_kernel<<<dim3(64, 8), 256, 0, stream>>>(qb, kb, vb, out);
}

// Round 2
// 270.952 us; speedup vs baseline: 1.3032x; 1.3032x over previous
//
#include <hip/hip_runtime.h>

#define TT 4096
#define CC 1024
#define DD 128

typedef __attribute__((ext_vector_type(8))) short s16x8;
typedef __attribute__((ext_vector_type(4))) short s16x4;
typedef __attribute__((ext_vector_type(8))) __bf16 bf16x8;
typedef __attribute__((ext_vector_type(4))) float f32x4;

__device__ __forceinline__ short f2bf(float f) {
    union { float f; unsigned u; } v; v.f = f;
    unsigned r = v.u + 0x7fffu + ((v.u >> 16) & 1u);
    return (short)(r >> 16);
}

__device__ __forceinline__ f32x4 mfma16(s16x8 a, s16x8 b, f32x4 c) {
    return __builtin_amdgcn_mfma_f32_16x16x32_bf16(
        __builtin_bit_cast(bf16x8, a), __builtin_bit_cast(bf16x8, b), c, 0, 0, 0);
}

__device__ __forceinline__ void gload_lds16(const short* g, short* l) {
    __builtin_amdgcn_global_load_lds(
        (const __attribute__((address_space(1))) void*)g,
        (__attribute__((address_space(3))) void*)l, 16, 0, 0);
}

// ---------------- kernel A: x fp32 -> bf16 (row-major, unchanged layout) --------
__global__ __launch_bounds__(256)
void xconv_kernel(const float* __restrict__ x, short* __restrict__ xb) {
    size_t i = ((size_t)blockIdx.x * 256 + threadIdx.x) * 8;
    float4 a = *(const float4*)(x + i);
    float4 b = *(const float4*)(x + i + 4);
    s16x8 r;
    r[0] = f2bf(a.x); r[1] = f2bf(a.y); r[2] = f2bf(a.z); r[3] = f2bf(a.w);
    r[4] = f2bf(b.x); r[5] = f2bf(b.y); r[6] = f2bf(b.z); r[7] = f2bf(b.w);
    *(s16x8*)(xb + i) = r;
}

// ---------------- kernel 0: transpose weights -> wT bf16 [3][D][C], scale wq ----
__global__ void wt_kernel(const float* __restrict__ wq, const float* __restrict__ wk,
                          const float* __restrict__ wv, short* __restrict__ wT) {
    int idx = blockIdx.x * 256 + threadIdx.x;   // 3*128*1024 = 393216 threads
    int d = idx & 127;
    int c = (idx >> 7) & 1023;
    int wsel = idx >> 17;
    const float* w = (wsel == 0) ? wq : (wsel == 1) ? wk : wv;
    float v = w[(size_t)c * DD + d];
    if (wsel == 0) v *= 0.08838834764831845f;   // D^-0.5 folded into Q
    wT[(size_t)wsel * DD * CC + (size_t)d * CC + c] = f2bf(v);
}

// ---------------- kernel 1: QKV projection GEMM (m97 structure) ------------------
// grid (256, 3): M-tile (128 rows), weight select. 4 waves, BM=128 BN=128 BK=64.
// Linear LDS + global_load_lds width=16; 2 barriers per K-iter.
__global__ __launch_bounds__(256)
void qkv_kernel(const short* __restrict__ xb, const short* __restrict__ wT,
                short* __restrict__ qo, short* __restrict__ ko, short* __restrict__ vTo) {
    __shared__ short lx[128 * 64];  // A tile, linear [row][64]
    __shared__ short lw[128 * 64];  // B tile (wT rows), linear [row][64]
    const int mt = blockIdx.x;
    const int wsel = blockIdx.y;
    const int tid = threadIdx.x;
    const int lane = tid & 63;
    const int wid = tid >> 6;
    const int l15 = lane & 15, g = lane >> 4;
    const short* wb = wT + (size_t)wsel * DD * CC;
    const short* xbase = xb + (size_t)mt * 128 * CC;

    const f32x4 fz = {0.f, 0.f, 0.f, 0.f};
    f32x4 acc[2][8];
#pragma unroll
    for (int mr = 0; mr < 2; mr++)
#pragma unroll
        for (int nr = 0; nr < 8; nr++) acc[mr][nr] = fz;

    // staging geometry: each wave stages rows [wid*32, wid*32+32) of both tiles,
    // 4 instrs each; one instr = 8 rows x 128B (lane>>3 = row, (lane&7)*16B = col)
    const int srow = wid * 32;
    const int lrow = lane >> 3;
    const int lcol = (lane & 7) * 8;

    for (int kc = 0; kc < CC / 64; kc++) {
        __syncthreads();   // previous iter's ds_reads done; LDS reusable
#pragma unroll
        for (int j = 0; j < 4; j++) {
            int row = srow + j * 8 + lrow;
            gload_lds16(xbase + (size_t)row * CC + kc * 64 + lcol, &lx[(srow + j * 8) * 64]);
            gload_lds16(wb    + (size_t)row * CC + kc * 64 + lcol, &lw[(srow + j * 8) * 64]);
        }
        __syncthreads();   // compiler drains vmcnt(0) before barrier -> tiles ready
#pragma unroll
        for (int ks = 0; ks < 2; ks++) {
            s16x8 af[2];
#pragma unroll
            for (int mr = 0; mr < 2; mr++)
                af[mr] = *(const s16x8*)&lx[(wid * 32 + mr * 16 + l15) * 64 + ks * 32 + g * 8];
#pragma unroll
            for (int nr = 0; nr < 8; nr++) {
                s16x8 bfg = *(const s16x8*)&lw[(nr * 16 + l15) * 64 + ks * 32 + g * 8];
#pragma unroll
                for (int mr = 0; mr < 2; mr++)
                    acc[mr][nr] = mfma16(af[mr], bfg, acc[mr][nr]);
            }
        }
    }
    // store: C/D layout row = 4*(lane>>4)+i, col = lane&15  [m89-verified]
    const int bidx = mt >> 5;           // batch (T/BM = 32 tiles per batch)
    const int t0 = (mt & 31) * 128;
#pragma unroll
    for (int mr = 0; mr < 2; mr++)
#pragma unroll
        for (int nr = 0; nr < 8; nr++)
#pragma unroll
            for (int i = 0; i < 4; i++) {
                int t = t0 + wid * 32 + mr * 16 + g * 4 + i;
                int d = nr * 16 + l15;
                short val = f2bf(acc[mr][nr][i]);
                if (wsel == 0)      qo[((size_t)bidx * TT + t) * DD + d] = val;
                else if (wsel == 1) ko[((size_t)bidx * TT + t) * DD + d] = val;
                else                vTo[((size_t)bidx * DD + d) * TT + t] = val;  // V^T
            }
}

// ---------------- kernel 2: causal flash attention (unchanged this round) --------
__global__ __launch_bounds__(256)
void attn_kernel(const short* __restrict__ qb, const short* __restrict__ kb,
                 const short* __restrict__ vb, float* __restrict__ out) {
    __shared__ short lk[8192];  // K tile [64][128] bf16, swizzled
    __shared__ short lv[8192];  // V^T tile [128][64] bf16, swizzled
    __shared__ short lp[4096];  // P per wave [16][64] bf16, swizzled
    const int qt = blockIdx.x, b = blockIdx.y;
    const int tid = threadIdx.x, lane = tid & 63, wid = tid >> 6;
    const int l15 = lane & 15, g = lane >> 4;
    const int qbase = qt * 64;
    const int wq0 = qbase + wid * 16;

    s16x8 qf[4];
    {
        const short* qp = qb + ((size_t)b * TT + wq0 + l15) * DD + g * 8;
#pragma unroll
        for (int ks = 0; ks < 4; ks++) qf[ks] = *(const s16x8*)(qp + ks * 32);
    }
    const f32x4 fz = {0.f, 0.f, 0.f, 0.f};
    f32x4 o[8];
#pragma unroll
    for (int n = 0; n < 8; n++) o[n] = fz;
    float rmax[4] = {-1e30f, -1e30f, -1e30f, -1e30f};
    float rsum[4] = {0.f, 0.f, 0.f, 0.f};

    for (int kvt = 0; kvt <= qt; kvt++) {
        const int kv0 = kvt * 64;
        __syncthreads();
#pragma unroll
        for (int j = 0; j < 4; j++) {
            int ci = j * 256 + tid;
            int r = ci >> 4, c8 = ci & 15;
            s16x8 t8 = *(const s16x8*)(kb + ((size_t)b * TT + kv0 + r) * DD + c8 * 8);
            int byte = (r * 256 + c8 * 16) ^ ((r & 7) << 4);
            *(s16x8*)((char*)lk + byte) = t8;
        }
#pragma unroll
        for (int j = 0; j < 4; j++) {
            int ci = j * 256 + tid;
            int d = ci >> 3, c8 = ci & 7;
            s16x8 t8 = *(const s16x8*)(vb + ((size_t)b * DD + d) * TT + kv0 + c8 * 8);
            int byte = (d * 128 + c8 * 16) ^ ((d & 7) << 4);
            *(s16x8*)((char*)lv + byte) = t8;
        }
        __syncthreads();
        if (kv0 > wq0 + 15) continue;

        f32x4 s[4];
#pragma unroll
        for (int sub = 0; sub < 4; sub++) {
            f32x4 a = fz;
#pragma unroll
            for (int ks = 0; ks < 4; ks++) {
                int row = sub * 16 + l15;
                int byte = (row * 256 + ks * 64 + g * 16) ^ ((row & 7) << 4);
                s16x8 kf = *(const s16x8*)((const char*)lk + byte);
                a = mfma16(qf[ks], kf, a);
            }
            s[sub] = a;
        }
        if (kv0 + 63 > wq0) {
#pragma unroll
            for (int sub = 0; sub < 4; sub++)
#pragma unroll
                for (int i = 0; i < 4; i++) {
                    int col = kv0 + sub * 16 + l15;
                    int row = wq0 + g * 4 + i;
                    if (col > row) s[sub][i] = -1e30f;
                }
        }
        float mnew[4], scal[4];
#pragma unroll
        for (int i = 0; i < 4; i++) {
            float m0 = fmaxf(fmaxf(s[0][i], s[1][i]), fmaxf(s[2][i], s[3][i]));
            m0 = fmaxf(m0, __shfl_xor(m0, 1));
            m0 = fmaxf(m0, __shfl_xor(m0, 2));
            m0 = fmaxf(m0, __shfl_xor(m0, 4));
            m0 = fmaxf(m0, __shfl_xor(m0, 8));
            mnew[i] = fmaxf(rmax[i], m0);
            scal[i] = __expf(rmax[i] - mnew[i]);
            rmax[i] = mnew[i];
        }
        float ls[4] = {0.f, 0.f, 0.f, 0.f};
#pragma unroll
        for (int sub = 0; sub < 4; sub++)
#pragma unroll
            for (int i = 0; i < 4; i++) {
                float p = __expf(s[sub][i] - mnew[i]);
                ls[i] += p;
                int prow = g * 4 + i;
                int byte = (wid * 2048 + prow * 128 + (sub * 16 + l15) * 2) ^ ((prow & 7) << 4);
                *(short*)((char*)lp + byte) = f2bf(p);
            }
#pragma unroll
        for (int i = 0; i < 4; i++) {
            float t = ls[i];
            t += __shfl_xor(t, 1);
            t += __shfl_xor(t, 2);
            t += __shfl_xor(t, 4);
            t += __shfl_xor(t, 8);
            rsum[i] = rsum[i] * scal[i] + t;
        }
#pragma unroll
        for (int n = 0; n < 8; n++)
#pragma unroll
            for (int i = 0; i < 4; i++) o[n][i] *= scal[i];
#pragma unroll
        for (int ks2 = 0; ks2 < 2; ks2++) {
            int pbyte = (wid * 2048 + l15 * 128 + ks2 * 64 + g * 16) ^ ((l15 & 7) << 4);
            s16x8 pf = *(const s16x8*)((const char*)lp + pbyte);
#pragma unroll
            for (int n = 0; n < 8; n++) {
                int vrow = n * 16 + l15;
                int vbyte = (vrow * 128 + ks2 * 64 + g * 16) ^ ((vrow & 7) << 4);
                s16x8 vf = *(const s16x8*)((const char*)lv + vbyte);
                o[n] = mfma16(pf, vf, o[n]);
            }
        }
    }
    float inv[4];
#pragma unroll
    for (int i = 0; i < 4; i++) inv[i] = 1.0f / rsum[i];
#pragma unroll
    for (int n = 0; n < 8; n++)
#pragma unroll
        for (int i = 0; i < 4; i++) {
            int row = wq0 + g * 4 + i;
            int d = n * 16 + l15;
            out[((size_t)b * TT + row) * DD + d] = o[n][i] * inv[i];
        }
}

// ---------------- launch ---------------------------------------------------------
extern "C" void kernel_launch(void* const* d_in, const int* in_sizes, int n_in,
                              void* d_out, int out_size, void* d_ws, size_t ws_size,
                              hipStream_t stream) {
    const float* x  = (const float*)d_in[0];
    const float* wq = (const float*)d_in[1];
    const float* wk = (const float*)d_in[2];
    const float* wv = (const float*)d_in[3];
    float* out = (float*)d_out;
    char* ws = (char*)d_ws;
    // ws layout: xb bf16 [8][4096][1024] (64MB) | wT bf16 [3][128][1024] (768KB)
    //            | q bf16 (8MB) | k bf16 (8MB) | vT bf16 [8][128][4096] (8MB) => ~89MB
    short* xbuf = (short*)ws;
    short* wT = (short*)(ws + 67108864);
    short* qb = (short*)(ws + 67108864 + 786432);
    short* kb = (short*)(ws + 67108864 + 786432 + 8388608);
    short* vb = (short*)(ws + 67108864 + 786432 + 16777216);

    xconv_kernel<<<16384, 256, 0, stream>>>(x, xbuf);
    wt_kernel<<<1536, 256, 0, stream>>>(wq, wk, wv, wT);
    qkv_kernel<<<dim3(256, 3), 256, 0, stream>>>(xbuf, wT, qb, kb, vb);
    attn_kernel<<<dim3(64, 8), 256, 0, stream>>>(qb, kb, vb, out);
}

// Round 3
// 224.875 us; speedup vs baseline: 1.5702x; 1.2049x over previous
//
#include <hip/hip_runtime.h>

#define TT 4096
#define CC 1024
#define DD 128

typedef __attribute__((ext_vector_type(8))) short s16x8;
typedef __attribute__((ext_vector_type(4))) short s16x4;
typedef __attribute__((ext_vector_type(8))) __bf16 bf16x8;
typedef __attribute__((ext_vector_type(4))) float f32x4;

__device__ __forceinline__ short f2bf(float f) {
    union { float f; unsigned u; } v; v.f = f;
    unsigned r = v.u + 0x7fffu + ((v.u >> 16) & 1u);
    return (short)(r >> 16);
}

__device__ __forceinline__ f32x4 mfma16(s16x8 a, s16x8 b, f32x4 c) {
    return __builtin_amdgcn_mfma_f32_16x16x32_bf16(
        __builtin_bit_cast(bf16x8, a), __builtin_bit_cast(bf16x8, b), c, 0, 0, 0);
}

__device__ __forceinline__ void gload_lds16(const short* g, short* l) {
    __builtin_amdgcn_global_load_lds(
        (const __attribute__((address_space(1))) void*)g,
        (__attribute__((address_space(3))) void*)l, 16, 0, 0);
}

// ---------------- kernel A: x fp32 -> bf16 (row-major, unchanged layout) --------
__global__ __launch_bounds__(256)
void xconv_kernel(const float* __restrict__ x, short* __restrict__ xb) {
    size_t i = ((size_t)blockIdx.x * 256 + threadIdx.x) * 8;
    float4 a = *(const float4*)(x + i);
    float4 b = *(const float4*)(x + i + 4);
    s16x8 r;
    r[0] = f2bf(a.x); r[1] = f2bf(a.y); r[2] = f2bf(a.z); r[3] = f2bf(a.w);
    r[4] = f2bf(b.x); r[5] = f2bf(b.y); r[6] = f2bf(b.z); r[7] = f2bf(b.w);
    *(s16x8*)(xb + i) = r;
}

// ---------------- kernel 0: transpose weights -> wT bf16 [3][D][C], scale wq ----
__global__ void wt_kernel(const float* __restrict__ wq, const float* __restrict__ wk,
                          const float* __restrict__ wv, short* __restrict__ wT) {
    int idx = blockIdx.x * 256 + threadIdx.x;   // 3*128*1024 = 393216 threads
    int d = idx & 127;
    int c = (idx >> 7) & 1023;
    int wsel = idx >> 17;
    const float* w = (wsel == 0) ? wq : (wsel == 1) ? wk : wv;
    float v = w[(size_t)c * DD + d];
    if (wsel == 0) v *= 0.08838834764831845f;   // D^-0.5 folded into Q
    wT[(size_t)wsel * DD * CC + (size_t)d * CC + c] = f2bf(v);
}

// ---------------- kernel 1: QKV projection GEMM (m97 structure, unchanged) ------
__global__ __launch_bounds__(256)
void qkv_kernel(const short* __restrict__ xb, const short* __restrict__ wT,
                short* __restrict__ qo, short* __restrict__ ko, short* __restrict__ vTo) {
    __shared__ short lx[128 * 64];  // A tile, linear [row][64]
    __shared__ short lw[128 * 64];  // B tile (wT rows), linear [row][64]
    const int mt = blockIdx.x;
    const int wsel = blockIdx.y;
    const int tid = threadIdx.x;
    const int lane = tid & 63;
    const int wid = tid >> 6;
    const int l15 = lane & 15, g = lane >> 4;
    const short* wb = wT + (size_t)wsel * DD * CC;
    const short* xbase = xb + (size_t)mt * 128 * CC;

    const f32x4 fz = {0.f, 0.f, 0.f, 0.f};
    f32x4 acc[2][8];
#pragma unroll
    for (int mr = 0; mr < 2; mr++)
#pragma unroll
        for (int nr = 0; nr < 8; nr++) acc[mr][nr] = fz;

    const int srow = wid * 32;
    const int lrow = lane >> 3;
    const int lcol = (lane & 7) * 8;

    for (int kc = 0; kc < CC / 64; kc++) {
        __syncthreads();
#pragma unroll
        for (int j = 0; j < 4; j++) {
            int row = srow + j * 8 + lrow;
            gload_lds16(xbase + (size_t)row * CC + kc * 64 + lcol, &lx[(srow + j * 8) * 64]);
            gload_lds16(wb    + (size_t)row * CC + kc * 64 + lcol, &lw[(srow + j * 8) * 64]);
        }
        __syncthreads();
#pragma unroll
        for (int ks = 0; ks < 2; ks++) {
            s16x8 af[2];
#pragma unroll
            for (int mr = 0; mr < 2; mr++)
                af[mr] = *(const s16x8*)&lx[(wid * 32 + mr * 16 + l15) * 64 + ks * 32 + g * 8];
#pragma unroll
            for (int nr = 0; nr < 8; nr++) {
                s16x8 bfg = *(const s16x8*)&lw[(nr * 16 + l15) * 64 + ks * 32 + g * 8];
#pragma unroll
                for (int mr = 0; mr < 2; mr++)
                    acc[mr][nr] = mfma16(af[mr], bfg, acc[mr][nr]);
            }
        }
    }
    const int bidx = mt >> 5;
    const int t0 = (mt & 31) * 128;
#pragma unroll
    for (int mr = 0; mr < 2; mr++)
#pragma unroll
        for (int nr = 0; nr < 8; nr++)
#pragma unroll
            for (int i = 0; i < 4; i++) {
                int t = t0 + wid * 32 + mr * 16 + g * 4 + i;
                int d = nr * 16 + l15;
                short val = f2bf(acc[mr][nr][i]);
                if (wsel == 0)      qo[((size_t)bidx * TT + t) * DD + d] = val;
                else if (wsel == 1) ko[((size_t)bidx * TT + t) * DD + d] = val;
                else                vTo[((size_t)bidx * DD + d) * TT + t] = val;  // V^T
            }
}

// ---------------- kernel 2: causal flash attention, swapped-operand -------------
// grid (64, 8) = (q-tile desc, batch). 4 waves x 16 q-rows, KVBLK=64, D=128.
// QK^T: mfma(K,Q) -> lane holds S[k-slice][q=l15] (row-local softmax, 2 shfl).
// PV:   mfma(V,P) -> O^T, rsum stays lane-local. K/V staged via global_load_lds
// with pre-swizzled global source (linear LDS dest + XOR-swizzled reads).
__global__ __launch_bounds__(256)
void attn_kernel(const short* __restrict__ qb, const short* __restrict__ kb,
                 const short* __restrict__ vb, float* __restrict__ out) {
    __shared__ short lk[64 * 128];   // K tile  [64 k][128 d] bf16, swizzled(bits4-6 by row&7)
    __shared__ short lv[128 * 64];   // V^T tile [128 d][64 k] bf16, swizzled
    __shared__ short lp[4 * 16 * 64];// P per wave [16 q][64 k] bf16, swizzled
    const int qt = 63 - blockIdx.x;  // heavy blocks dispatch first (load balance)
    const int b = blockIdx.y;
    const int tid = threadIdx.x, lane = tid & 63, wid = tid >> 6;
    const int l15 = lane & 15, g = lane >> 4;
    const int qbase = qt * 64;
    const int wq0 = qbase + wid * 16;

    // hoist Q fragments (pre-scaled by D^-0.5): B-frag = Q[q=l15][d0=ks*32+8g]
    s16x8 qf[4];
    {
        const short* qp = qb + ((size_t)b * TT + wq0 + l15) * DD + g * 8;
#pragma unroll
        for (int ks = 0; ks < 4; ks++) qf[ks] = *(const s16x8*)(qp + ks * 32);
    }
    const f32x4 fz = {0.f, 0.f, 0.f, 0.f};
    f32x4 o[8];      // O^T: o[n][i] = O[q=wq0+l15][d=n*16+4g+i]
#pragma unroll
    for (int n = 0; n < 8; n++) o[n] = fz;
    float rmax = -1e30f, rsum = 0.f;

    // staging geometry (per wave): K rows [wid*16, +16), 4 insts x 4 rows;
    //                              V rows [wid*32, +32), 4 insts x 8 rows.
    const short* kTile0 = kb + (size_t)b * TT * DD;
    const short* vTile0 = vb + (size_t)b * DD * TT;

    for (int kvt = 0; kvt <= qt; kvt++) {
        const int kv0 = kvt * 64;
        __syncthreads();   // prev iter's LDS reads done
#pragma unroll
        for (int j = 0; j < 4; j++) {
            // K: 4 rows/inst; lane loads pre-swizzled 16B chunk of row r
            int rbk = wid * 16 + j * 4;
            int rk = rbk + (lane >> 4);
            int ck = (lane & 15) ^ (rk & 7);
            gload_lds16(kTile0 + (size_t)(kv0 + rk) * DD + ck * 8, lk + rbk * 128);
            // V: 8 rows/inst
            int rbv = wid * 32 + j * 8;
            int dv = rbv + (lane >> 3);
            int cv = (lane & 7) ^ (dv & 7);
            gload_lds16(vTile0 + (size_t)dv * TT + kv0 + cv * 8, lv + rbv * 64);
        }
        __syncthreads();   // vmcnt(0) drained by compiler before barrier
        if (kv0 > wq0 + 15) continue;   // wave entirely above diagonal

        // S^T = K Q^T : s[sub][i] = S[k=kv0+sub*16+4g+i][q=wq0+l15]
        f32x4 s[4];
        __builtin_amdgcn_s_setprio(1);
#pragma unroll
        for (int sub = 0; sub < 4; sub++) {
            f32x4 a = fz;
#pragma unroll
            for (int ks = 0; ks < 4; ks++) {
                int row = sub * 16 + l15;
                int byte = (row * 256 + ks * 64 + g * 16) ^ ((row & 7) << 4);
                s16x8 kf = *(const s16x8*)((const char*)lk + byte);
                a = mfma16(kf, qf[ks], a);   // A=K rows, B=Q rows
            }
            s[sub] = a;
        }
        __builtin_amdgcn_s_setprio(0);
        // causal mask: only the diagonal supertile straddles
        if (kvt == qt) {
#pragma unroll
            for (int sub = 0; sub < 4; sub++)
#pragma unroll
                for (int i = 0; i < 4; i++) {
                    int k = kv0 + sub * 16 + 4 * g + i;
                    if (k > wq0 + l15) s[sub][i] = -1e30f;
                }
        }
        // online softmax — lane-local row (q = wq0+l15), reduce over 4 lane-group
        float m0 = s[0][0];
#pragma unroll
        for (int sub = 0; sub < 4; sub++)
#pragma unroll
            for (int i = 0; i < 4; i++) m0 = fmaxf(m0, s[sub][i]);
        m0 = fmaxf(m0, __shfl_xor(m0, 16));
        m0 = fmaxf(m0, __shfl_xor(m0, 32));
        float mnew = fmaxf(rmax, m0);
        float scal = __expf(rmax - mnew);
        rmax = mnew;
        float ls = 0.f;
#pragma unroll
        for (int sub = 0; sub < 4; sub++)
#pragma unroll
            for (int i = 0; i < 4; i++) {
                float p = __expf(s[sub][i] - mnew);
                s[sub][i] = p;
                ls += p;
            }
        ls += __shfl_xor(ls, 16);
        ls += __shfl_xor(ls, 32);
        rsum = rsum * scal + ls;
        // P -> bf16, vectorized LDS write: per sub one ds_write_b64 (k=sub*16+4g..+3)
#pragma unroll
        for (int sub = 0; sub < 4; sub++) {
            unsigned w0 = (unsigned)(unsigned short)f2bf(s[sub][0]) |
                          ((unsigned)(unsigned short)f2bf(s[sub][1]) << 16);
            unsigned w1 = (unsigned)(unsigned short)f2bf(s[sub][2]) |
                          ((unsigned)(unsigned short)f2bf(s[sub][3]) << 16);
            uint2 w01 = {w0, w1};
            int byte = (l15 * 128 + sub * 32 + g * 8) ^ ((l15 & 7) << 4);
            *(uint2*)((char*)lp + wid * 2048 + byte) = w01;
        }
        // rescale O by scal (lane-local)
#pragma unroll
        for (int n = 0; n < 8; n++)
#pragma unroll
            for (int i = 0; i < 4; i++) o[n][i] *= scal;
        // PV swapped: O^T += V^T_tile (A, rows=d) x P^T (B, cols=q)
        __builtin_amdgcn_s_setprio(1);
#pragma unroll
        for (int ks2 = 0; ks2 < 2; ks2++) {
            int pbyte = (l15 * 128 + ks2 * 64 + g * 16) ^ ((l15 & 7) << 4);
            s16x8 pf = *(const s16x8*)((const char*)lp + wid * 2048 + pbyte);
#pragma unroll
            for (int n = 0; n < 8; n++) {
                int vrow = n * 16 + l15;
                int vbyte = (vrow * 128 + ks2 * 64 + g * 16) ^ ((vrow & 7) << 4);
                s16x8 vf = *(const s16x8*)((const char*)lv + vbyte);
                o[n] = mfma16(vf, pf, o[n]);   // A=V rows(d), B=P cols(q)
            }
        }
        __builtin_amdgcn_s_setprio(0);
    }
    // epilogue: O[q=wq0+l15][d=n*16+4g+i] = o[n][i]/rsum ; float4 stores
    float inv = 1.0f / rsum;
    float* orow = out + ((size_t)b * TT + wq0 + l15) * DD;
#pragma unroll
    for (int n = 0; n < 8; n++) {
        float4 r;
        r.x = o[n][0] * inv; r.y = o[n][1] * inv;
        r.z = o[n][2] * inv; r.w = o[n][3] * inv;
        *(float4*)(orow + n * 16 + 4 * g) = r;
    }
}

// ---------------- launch ---------------------------------------------------------
extern "C" void kernel_launch(void* const* d_in, const int* in_sizes, int n_in,
                              void* d_out, int out_size, void* d_ws, size_t ws_size,
                              hipStream_t stream) {
    const float* x  = (const float*)d_in[0];
    const float* wq = (const float*)d_in[1];
    const float* wk = (const float*)d_in[2];
    const float* wv = (const float*)d_in[3];
    float* out = (float*)d_out;
    char* ws = (char*)d_ws;
    short* xbuf = (short*)ws;
    short* wT = (short*)(ws + 67108864);
    short* qb = (short*)(ws + 67108864 + 786432);
    short* kb = (short*)(ws + 67108864 + 786432 + 8388608);
    short* vb = (short*)(ws + 67108864 + 786432 + 16777216);

    xconv_kernel<<<16384, 256, 0, stream>>>(x, xbuf);
    wt_kernel<<<1536, 256, 0, stream>>>(wq, wk, wv, wT);
    qkv_kernel<<<dim3(256, 3), 256, 0, stream>>>(xbuf, wT, qb, kb, vb);
    attn_kernel<<<dim3(64, 8), 256, 0, stream>>>(qb, kb, vb, out);
}

// Round 4
// 181.515 us; speedup vs baseline: 1.9453x; 1.2389x over previous
//
#include <hip/hip_runtime.h>

#define TT 4096
#define CC 1024
#define DD 128

typedef __attribute__((ext_vector_type(8))) short s16x8;
typedef __attribute__((ext_vector_type(4))) short s16x4;
typedef __attribute__((ext_vector_type(8))) __bf16 bf16x8;
typedef __attribute__((ext_vector_type(4))) float f32x4;

__device__ __forceinline__ short f2bf(float f) {
    union { float f; unsigned u; } v; v.f = f;
    unsigned r = v.u + 0x7fffu + ((v.u >> 16) & 1u);
    return (short)(r >> 16);
}

__device__ __forceinline__ unsigned cvt_pk(float lo, float hi) {
    unsigned r;
    asm("v_cvt_pk_bf16_f32 %0, %1, %2" : "=v"(r) : "v"(lo), "v"(hi));
    return r;
}

__device__ __forceinline__ f32x4 mfma16(s16x8 a, s16x8 b, f32x4 c) {
    return __builtin_amdgcn_mfma_f32_16x16x32_bf16(
        __builtin_bit_cast(bf16x8, a), __builtin_bit_cast(bf16x8, b), c, 0, 0, 0);
}

__device__ __forceinline__ void gload_lds16(const short* g, short* l) {
    __builtin_amdgcn_global_load_lds(
        (const __attribute__((address_space(1))) void*)g,
        (__attribute__((address_space(3))) void*)l, 16, 0, 0);
}

// ---------------- kernel 0: transpose weights -> wT bf16 [3][D][C], scale wq ----
__global__ void wt_kernel(const float* __restrict__ wq, const float* __restrict__ wk,
                          const float* __restrict__ wv, short* __restrict__ wT) {
    int idx = blockIdx.x * 256 + threadIdx.x;   // 3*128*1024 = 393216 threads
    int d = idx & 127;
    int c = (idx >> 7) & 1023;
    int wsel = idx >> 17;
    const float* w = (wsel == 0) ? wq : (wsel == 1) ? wk : wv;
    float v = w[(size_t)c * DD + d];
    if (wsel == 0) v *= 0.08838834764831845f;   // D^-0.5 folded into Q
    wT[(size_t)wsel * DD * CC + (size_t)d * CC + c] = f2bf(v);
}

// ---------------- kernel 1: fused QKV projection GEMM ----------------------------
// 256 blocks x 512 threads (8 waves: wm=wid>>1 in 0..3, wn=wid&1 in 0..1).
// BM=128, BN=384 (q|k|v fused), BK=64. A fp32->reg->bf16 (no LDS, exact frag
// layout); W double-buffered via global_load_lds. x read exactly once (fp32).
__global__ __launch_bounds__(512)
void qkv_kernel(const float* __restrict__ x, const short* __restrict__ wT,
                short* __restrict__ qo, short* __restrict__ ko, short* __restrict__ vTo) {
    __shared__ short lw[2][384 * 64];   // 2 x 48KB
    const int mt = blockIdx.x;
    const int tid = threadIdx.x, lane = tid & 63, wid = tid >> 6;
    const int l15 = lane & 15, g = lane >> 4;
    const int wm = wid >> 1, wn = wid & 1;
    const int arow = mt * 128 + wm * 32 + l15;          // + mr*16
    const float* xr0 = x + (size_t)arow * CC + g * 8;
    const float* xr1 = xr0 + (size_t)16 * CC;

    const f32x4 fz = {0.f, 0.f, 0.f, 0.f};
    f32x4 acc[2][12];
#pragma unroll
    for (int mr = 0; mr < 2; mr++)
#pragma unroll
        for (int nr = 0; nr < 12; nr++) acc[mr][nr] = fz;

    // W staging: wave stages rows [wid*48, +48), 6 insts x (8 rows x 128B)
    const int swr = wid * 48;
    const short* wsrc = wT + (size_t)(swr + (lane >> 3)) * CC + (lane & 7) * 8;

    float4 pa[2][2][2];   // prefetched A fp32 [mr][ks][half]
#define LOADA(kc) do { \
    _Pragma("unroll") for (int mr_ = 0; mr_ < 2; mr_++) \
    _Pragma("unroll") for (int ks_ = 0; ks_ < 2; ks_++) { \
        const float* p_ = (mr_ ? xr1 : xr0) + (kc) * 64 + ks_ * 32; \
        pa[mr_][ks_][0] = *(const float4*)p_; \
        pa[mr_][ks_][1] = *(const float4*)(p_ + 4); } \
} while (0)
#define STAGEW(kc, buf) do { \
    _Pragma("unroll") for (int j_ = 0; j_ < 6; j_++) \
        gload_lds16(wsrc + (size_t)(j_ * 8) * CC + (kc) * 64, &lw[buf][(swr + j_ * 8) * 64]); \
} while (0)

    LOADA(0);
    STAGEW(0, 0);
    asm volatile("s_waitcnt vmcnt(0)" ::: "memory");
    __builtin_amdgcn_s_barrier();
    int cur = 0;

    for (int kc = 0; kc < 16; kc++) {
        // convert prefetched A -> bf16 fragments
        s16x8 af[2][2];
#pragma unroll
        for (int mr = 0; mr < 2; mr++)
#pragma unroll
            for (int ks = 0; ks < 2; ks++) {
                union { unsigned u[4]; s16x8 v; } cv;
                cv.u[0] = cvt_pk(pa[mr][ks][0].x, pa[mr][ks][0].y);
                cv.u[1] = cvt_pk(pa[mr][ks][0].z, pa[mr][ks][0].w);
                cv.u[2] = cvt_pk(pa[mr][ks][1].x, pa[mr][ks][1].y);
                cv.u[3] = cvt_pk(pa[mr][ks][1].z, pa[mr][ks][1].w);
                af[mr][ks] = cv.v;
            }
        if (kc < 15) { LOADA(kc + 1); STAGEW(kc + 1, cur ^ 1); }
        __builtin_amdgcn_s_setprio(1);
#pragma unroll
        for (int ks = 0; ks < 2; ks++)
#pragma unroll
            for (int nr = 0; nr < 12; nr++) {
                const s16x8 bfg = *(const s16x8*)
                    &lw[cur][(wn * 192 + nr * 16 + l15) * 64 + ks * 32 + g * 8];
                acc[0][nr] = mfma16(af[0][ks], bfg, acc[0][nr]);
                acc[1][nr] = mfma16(af[1][ks], bfg, acc[1][nr]);
            }
        __builtin_amdgcn_s_setprio(0);
        asm volatile("s_waitcnt vmcnt(0) lgkmcnt(0)" ::: "memory");
        __builtin_amdgcn_s_barrier();
        cur ^= 1;
    }

    // store: C/D layout row = 4g+i, col = l15
    const int bidx = mt >> 5;
    const int tb = (mt & 31) * 128 + wm * 32;
#pragma unroll
    for (int mr = 0; mr < 2; mr++)
#pragma unroll
        for (int nr = 0; nr < 12; nr++) {
            const int n = wn * 192 + nr * 16 + l15;
            if (n < 256) {   // uniform per (wn,nr): boundaries are 16-aligned
                short* dst; int d;
                if (n < 128) { dst = qo; d = n; } else { dst = ko; d = n - 128; }
#pragma unroll
                for (int i = 0; i < 4; i++) {
                    int t = tb + mr * 16 + g * 4 + i;
                    dst[((size_t)bidx * TT + t) * DD + d] = f2bf(acc[mr][nr][i]);
                }
            } else {
                const int d = n - 256;
                const int t = tb + mr * 16 + g * 4;
                uint2 u;
                u.x = cvt_pk(acc[mr][nr][0], acc[mr][nr][1]);
                u.y = cvt_pk(acc[mr][nr][2], acc[mr][nr][3]);
                *(uint2*)(vTo + ((size_t)bidx * DD + d) * TT + t) = u;   // V^T, 8B aligned
            }
        }
}

// ---------------- kernel 2: causal flash attention, swapped-operand + dbuf -------
// grid (64, 8). 4 waves x 16 q-rows, KVBLK=64. 2-phase pipeline: prefetch tile
// t+1 into buf^1 while computing t; raw s_barrier + manual vmcnt/lgkm drain.
__device__ __forceinline__ void attn_stage(const short* kT, const short* vT, int kv0,
                                           short* lkb, short* lvb, int wid, int lane) {
#pragma unroll
    for (int j = 0; j < 4; j++) {
        int rbk = wid * 16 + j * 4;
        int rk = rbk + (lane >> 4);
        int ck = (lane & 15) ^ (rk & 7);
        gload_lds16(kT + (size_t)(kv0 + rk) * DD + ck * 8, lkb + rbk * 128);
        int rbv = wid * 32 + j * 8;
        int dv = rbv + (lane >> 3);
        int cv = (lane & 7) ^ (dv & 7);
        gload_lds16(vT + (size_t)dv * TT + kv0 + cv * 8, lvb + rbv * 64);
    }
}

__global__ __launch_bounds__(256)
void attn_kernel(const short* __restrict__ qb, const short* __restrict__ kb,
                 const short* __restrict__ vb, float* __restrict__ out) {
    __shared__ short lk[2][64 * 128];   // K tiles, swizzled chunks
    __shared__ short lv[2][128 * 64];   // V^T tiles, swizzled chunks
    __shared__ short lp[4 * 16 * 64];   // P per wave
    const int qt = 63 - blockIdx.x;     // heavy blocks dispatch first
    const int b = blockIdx.y;
    const int tid = threadIdx.x, lane = tid & 63, wid = tid >> 6;
    const int l15 = lane & 15, g = lane >> 4;
    const int wq0 = qt * 64 + wid * 16;

    s16x8 qf[4];
    {
        const short* qp = qb + ((size_t)b * TT + wq0 + l15) * DD + g * 8;
#pragma unroll
        for (int ks = 0; ks < 4; ks++) qf[ks] = *(const s16x8*)(qp + ks * 32);
    }
    const f32x4 fz = {0.f, 0.f, 0.f, 0.f};
    f32x4 o[8];
#pragma unroll
    for (int n = 0; n < 8; n++) o[n] = fz;
    float rmax = -1e30f, rsum = 0.f;

    const short* kT = kb + (size_t)b * TT * DD;
    const short* vT = vb + (size_t)b * DD * TT;

    attn_stage(kT, vT, 0, lk[0], lv[0], wid, lane);
    asm volatile("s_waitcnt vmcnt(0)" ::: "memory");
    __builtin_amdgcn_s_barrier();
    int cur = 0;

    for (int kvt = 0; kvt <= qt; kvt++) {
        if (kvt < qt) attn_stage(kT, vT, (kvt + 1) * 64, lk[cur ^ 1], lv[cur ^ 1], wid, lane);
        const int kv0 = kvt * 64;
        const char* lkc = (const char*)&lk[cur][0];
        const char* lvc = (const char*)&lv[cur][0];

        // S^T = K Q^T : s[sub][i] = S[k=kv0+sub*16+4g+i][q=wq0+l15]
        f32x4 s[4];
        __builtin_amdgcn_s_setprio(1);
#pragma unroll
        for (int sub = 0; sub < 4; sub++) {
            f32x4 a = fz;
#pragma unroll
            for (int ks = 0; ks < 4; ks++) {
                int row = sub * 16 + l15;
                int byte = (row * 256 + ks * 64 + g * 16) ^ ((row & 7) << 4);
                s16x8 kf = *(const s16x8*)(lkc + byte);
                a = mfma16(kf, qf[ks], a);
            }
            s[sub] = a;
        }
        __builtin_amdgcn_s_setprio(0);
        if (kvt == qt) {   // causal mask on diagonal supertile
#pragma unroll
            for (int sub = 0; sub < 4; sub++)
#pragma unroll
                for (int i = 0; i < 4; i++) {
                    int k = kv0 + sub * 16 + 4 * g + i;
                    if (k > wq0 + l15) s[sub][i] = -1e30f;
                }
        }
        // online softmax, lane-local q-row
        float m0 = s[0][0];
#pragma unroll
        for (int sub = 0; sub < 4; sub++)
#pragma unroll
            for (int i = 0; i < 4; i++) m0 = fmaxf(m0, s[sub][i]);
        m0 = fmaxf(m0, __shfl_xor(m0, 16));
        m0 = fmaxf(m0, __shfl_xor(m0, 32));
        float mnew = fmaxf(rmax, m0);
        float scal = __expf(rmax - mnew);
        rmax = mnew;
        float ls = 0.f;
#pragma unroll
        for (int sub = 0; sub < 4; sub++)
#pragma unroll
            for (int i = 0; i < 4; i++) {
                float p = __expf(s[sub][i] - mnew);
                s[sub][i] = p;
                ls += p;
            }
        ls += __shfl_xor(ls, 16);
        ls += __shfl_xor(ls, 32);
        rsum = rsum * scal + ls;
        // P -> bf16 -> LDS (one ds_write_b64 per sub)
#pragma unroll
        for (int sub = 0; sub < 4; sub++) {
            uint2 w01;
            w01.x = cvt_pk(s[sub][0], s[sub][1]);
            w01.y = cvt_pk(s[sub][2], s[sub][3]);
            int byte = (l15 * 128 + sub * 32 + g * 8) ^ ((l15 & 7) << 4);
            *(uint2*)((char*)lp + wid * 2048 + byte) = w01;
        }
#pragma unroll
        for (int n = 0; n < 8; n++)
#pragma unroll
            for (int i = 0; i < 4; i++) o[n][i] *= scal;
        // PV swapped: O^T += V^T (A, rows=d) x P^T (B, cols=q)
        __builtin_amdgcn_s_setprio(1);
#pragma unroll
        for (int ks2 = 0; ks2 < 2; ks2++) {
            int pbyte = (l15 * 128 + ks2 * 64 + g * 16) ^ ((l15 & 7) << 4);
            s16x8 pf = *(const s16x8*)((const char*)lp + wid * 2048 + pbyte);
#pragma unroll
            for (int n = 0; n < 8; n++) {
                int vrow = n * 16 + l15;
                int vbyte = (vrow * 128 + ks2 * 64 + g * 16) ^ ((vrow & 7) << 4);
                s16x8 vf = *(const s16x8*)(lvc + vbyte);
                o[n] = mfma16(vf, pf, o[n]);
            }
        }
        __builtin_amdgcn_s_setprio(0);
        asm volatile("s_waitcnt vmcnt(0) lgkmcnt(0)" ::: "memory");
        __builtin_amdgcn_s_barrier();
        cur ^= 1;
    }
    float inv = 1.0f / rsum;
    float* orow = out + ((size_t)b * TT + wq0 + l15) * DD;
#pragma unroll
    for (int n = 0; n < 8; n++) {
        float4 r;
        r.x = o[n][0] * inv; r.y = o[n][1] * inv;
        r.z = o[n][2] * inv; r.w = o[n][3] * inv;
        *(float4*)(orow + n * 16 + 4 * g) = r;
    }
}

// ---------------- launch ---------------------------------------------------------
extern "C" void kernel_launch(void* const* d_in, const int* in_sizes, int n_in,
                              void* d_out, int out_size, void* d_ws, size_t ws_size,
                              hipStream_t stream) {
    const float* x  = (const float*)d_in[0];
    const float* wq = (const float*)d_in[1];
    const float* wk = (const float*)d_in[2];
    const float* wv = (const float*)d_in[3];
    float* out = (float*)d_out;
    char* ws = (char*)d_ws;
    // ws: wT bf16 [384][1024] (768KB) | q bf16 (8MB) | k bf16 (8MB) | vT bf16 (8MB)
    short* wT = (short*)ws;
    short* qb = (short*)(ws + 786432);
    short* kb = (short*)(ws + 786432 + 8388608);
    short* vb = (short*)(ws + 786432 + 16777216);

    wt_kernel<<<1536, 256, 0, stream>>>(wq, wk, wv, wT);
    qkv_kernel<<<256, 512, 0, stream>>>(x, wT, qb, kb, vb);
    attn_kernel<<<dim3(64, 8), 256, 0, stream>>>(qb, kb, vb, out);
}

// Round 5
// 168.293 us; speedup vs baseline: 2.0982x; 1.0786x over previous
//
#include <hip/hip_runtime.h>

#define TT 4096
#define CC 1024
#define DD 128

typedef __attribute__((ext_vector_type(8))) short s16x8;
typedef __attribute__((ext_vector_type(4))) short s16x4;
typedef __attribute__((ext_vector_type(8))) __bf16 bf16x8;
typedef __attribute__((ext_vector_type(4))) float f32x4;

__device__ __forceinline__ short f2bf(float f) {
    union { float f; unsigned u; } v; v.f = f;
    unsigned r = v.u + 0x7fffu + ((v.u >> 16) & 1u);
    return (short)(r >> 16);
}

__device__ __forceinline__ unsigned cvt_pk(float lo, float hi) {
    unsigned r;
    asm("v_cvt_pk_bf16_f32 %0, %1, %2" : "=v"(r) : "v"(lo), "v"(hi));
    return r;
}

__device__ __forceinline__ f32x4 mfma16(s16x8 a, s16x8 b, f32x4 c) {
    return __builtin_amdgcn_mfma_f32_16x16x32_bf16(
        __builtin_bit_cast(bf16x8, a), __builtin_bit_cast(bf16x8, b), c, 0, 0, 0);
}

__device__ __forceinline__ void gload_lds16(const short* g, short* l) {
    __builtin_amdgcn_global_load_lds(
        (const __attribute__((address_space(1))) void*)g,
        (__attribute__((address_space(3))) void*)l, 16, 0, 0);
}

// ---------------- kernel 0: transpose weights -> wT bf16 [3][D][C], scale wq ----
__global__ void wt_kernel(const float* __restrict__ wq, const float* __restrict__ wk,
                          const float* __restrict__ wv, short* __restrict__ wT) {
    int idx = blockIdx.x * 256 + threadIdx.x;   // 3*128*1024 = 393216 threads
    int d = idx & 127;
    int c = (idx >> 7) & 1023;
    int wsel = idx >> 17;
    const float* w = (wsel == 0) ? wq : (wsel == 1) ? wk : wv;
    float v = w[(size_t)c * DD + d];
    if (wsel == 0) v *= 0.08838834764831845f;   // D^-0.5 folded into Q
    wT[(size_t)wsel * DD * CC + (size_t)d * CC + c] = f2bf(v);
}

// ---------------- kernel 1: fused QKV projection GEMM (unchanged) ----------------
__global__ __launch_bounds__(512)
void qkv_kernel(const float* __restrict__ x, const short* __restrict__ wT,
                short* __restrict__ qo, short* __restrict__ ko, short* __restrict__ vTo) {
    __shared__ short lw[2][384 * 64];   // 2 x 48KB
    const int mt = blockIdx.x;
    const int tid = threadIdx.x, lane = tid & 63, wid = tid >> 6;
    const int l15 = lane & 15, g = lane >> 4;
    const int wm = wid >> 1, wn = wid & 1;
    const int arow = mt * 128 + wm * 32 + l15;
    const float* xr0 = x + (size_t)arow * CC + g * 8;
    const float* xr1 = xr0 + (size_t)16 * CC;

    const f32x4 fz = {0.f, 0.f, 0.f, 0.f};
    f32x4 acc[2][12];
#pragma unroll
    for (int mr = 0; mr < 2; mr++)
#pragma unroll
        for (int nr = 0; nr < 12; nr++) acc[mr][nr] = fz;

    const int swr = wid * 48;
    const short* wsrc = wT + (size_t)(swr + (lane >> 3)) * CC + (lane & 7) * 8;

    float4 pa[2][2][2];
#define LOADA(kc) do { \
    _Pragma("unroll") for (int mr_ = 0; mr_ < 2; mr_++) \
    _Pragma("unroll") for (int ks_ = 0; ks_ < 2; ks_++) { \
        const float* p_ = (mr_ ? xr1 : xr0) + (kc) * 64 + ks_ * 32; \
        pa[mr_][ks_][0] = *(const float4*)p_; \
        pa[mr_][ks_][1] = *(const float4*)(p_ + 4); } \
} while (0)
#define STAGEW(kc, buf) do { \
    _Pragma("unroll") for (int j_ = 0; j_ < 6; j_++) \
        gload_lds16(wsrc + (size_t)(j_ * 8) * CC + (kc) * 64, &lw[buf][(swr + j_ * 8) * 64]); \
} while (0)

    LOADA(0);
    STAGEW(0, 0);
    asm volatile("s_waitcnt vmcnt(0)" ::: "memory");
    __builtin_amdgcn_s_barrier();
    int cur = 0;

    for (int kc = 0; kc < 16; kc++) {
        s16x8 af[2][2];
#pragma unroll
        for (int mr = 0; mr < 2; mr++)
#pragma unroll
            for (int ks = 0; ks < 2; ks++) {
                union { unsigned u[4]; s16x8 v; } cv;
                cv.u[0] = cvt_pk(pa[mr][ks][0].x, pa[mr][ks][0].y);
                cv.u[1] = cvt_pk(pa[mr][ks][0].z, pa[mr][ks][0].w);
                cv.u[2] = cvt_pk(pa[mr][ks][1].x, pa[mr][ks][1].y);
                cv.u[3] = cvt_pk(pa[mr][ks][1].z, pa[mr][ks][1].w);
                af[mr][ks] = cv.v;
            }
        if (kc < 15) { LOADA(kc + 1); STAGEW(kc + 1, cur ^ 1); }
        __builtin_amdgcn_s_setprio(1);
#pragma unroll
        for (int ks = 0; ks < 2; ks++)
#pragma unroll
            for (int nr = 0; nr < 12; nr++) {
                const s16x8 bfg = *(const s16x8*)
                    &lw[cur][(wn * 192 + nr * 16 + l15) * 64 + ks * 32 + g * 8];
                acc[0][nr] = mfma16(af[0][ks], bfg, acc[0][nr]);
                acc[1][nr] = mfma16(af[1][ks], bfg, acc[1][nr]);
            }
        __builtin_amdgcn_s_setprio(0);
        asm volatile("s_waitcnt vmcnt(0) lgkmcnt(0)" ::: "memory");
        __builtin_amdgcn_s_barrier();
        cur ^= 1;
    }

    const int bidx = mt >> 5;
    const int tb = (mt & 31) * 128 + wm * 32;
#pragma unroll
    for (int mr = 0; mr < 2; mr++)
#pragma unroll
        for (int nr = 0; nr < 12; nr++) {
            const int n = wn * 192 + nr * 16 + l15;
            if (n < 256) {
                short* dst; int d;
                if (n < 128) { dst = qo; d = n; } else { dst = ko; d = n - 128; }
#pragma unroll
                for (int i = 0; i < 4; i++) {
                    int t = tb + mr * 16 + g * 4 + i;
                    dst[((size_t)bidx * TT + t) * DD + d] = f2bf(acc[mr][nr][i]);
                }
            } else {
                const int d = n - 256;
                const int t = tb + mr * 16 + g * 4;
                uint2 u;
                u.x = cvt_pk(acc[mr][nr][0], acc[mr][nr][1]);
                u.y = cvt_pk(acc[mr][nr][2], acc[mr][nr][3]);
                *(uint2*)(vTo + ((size_t)bidx * DD + d) * TT + t) = u;   // V^T
            }
        }
}

// ---------------- kernel 2: paired-tile causal flash attention -------------------
// 256 blocks x 512 threads. Block id: b = id&7 (batch -> one batch per XCD),
// p = id>>3 in 0..31. Waves 0-3 own q-tile p, waves 4-7 own q-tile 63-p:
// per-SIMD work = (p+1) + (64-p) = 65 wave-iters on EVERY block -> balanced
// independent of scheduler placement. K/V staged once, shared by both tiles.
__device__ __forceinline__ void attn_stage8(const short* kT, const short* vT, int kv0,
                                            short* lkb, short* lvb, int wid, int lane) {
#pragma unroll
    for (int j = 0; j < 2; j++) {
        int rbk = wid * 8 + j * 4;                 // K: 8 rows/wave, 4 rows/inst
        int rk = rbk + (lane >> 4);
        int ck = (lane & 15) ^ (rk & 7);
        gload_lds16(kT + (size_t)(kv0 + rk) * DD + ck * 8, lkb + rbk * 128);
        int rbv = wid * 16 + j * 8;                // V: 16 rows/wave, 8 rows/inst
        int dv = rbv + (lane >> 3);
        int cv = (lane & 7) ^ (dv & 7);
        gload_lds16(vT + (size_t)dv * TT + kv0 + cv * 8, lvb + rbv * 64);
    }
}

__global__ __launch_bounds__(512)
void attn_kernel(const short* __restrict__ qb, const short* __restrict__ kb,
                 const short* __restrict__ vb, float* __restrict__ out) {
    __shared__ short lk[2][64 * 128];   // 32KB  K tiles, swizzled chunks
    __shared__ short lv[2][128 * 64];   // 32KB  V^T tiles, swizzled chunks
    __shared__ short lp[8 * 16 * 64];   // 16KB  P per wave
    const int id = blockIdx.x;
    const int b = id & 7;               // batch -> XCD-local K/V in L2
    const int p = id >> 3;              // 0..31
    const int tid = threadIdx.x, lane = tid & 63, wid = tid >> 6;
    const int l15 = lane & 15, g = lane >> 4;
    const int qt_w = (wid < 4) ? p : 63 - p;       // this wave's q-tile
    const int wq0 = qt_w * 64 + (wid & 3) * 16;    // this wave's 16 q-rows
    const int tmax = 63 - p;                       // last kv tile any wave needs

    s16x8 qf[4];
    {
        const short* qp = qb + ((size_t)b * TT + wq0 + l15) * DD + g * 8;
#pragma unroll
        for (int ks = 0; ks < 4; ks++) qf[ks] = *(const s16x8*)(qp + ks * 32);
    }
    const f32x4 fz = {0.f, 0.f, 0.f, 0.f};
    f32x4 o[8];
#pragma unroll
    for (int n = 0; n < 8; n++) o[n] = fz;
    float rmax = -1e30f, rsum = 0.f;

    const short* kT = kb + (size_t)b * TT * DD;
    const short* vT = vb + (size_t)b * DD * TT;

    attn_stage8(kT, vT, 0, lk[0], lv[0], wid, lane);
    asm volatile("s_waitcnt vmcnt(0)" ::: "memory");
    __builtin_amdgcn_s_barrier();
    int cur = 0;

    for (int t = 0; t <= tmax; t++) {
        if (t < tmax) attn_stage8(kT, vT, (t + 1) * 64, lk[cur ^ 1], lv[cur ^ 1], wid, lane);
        if (t <= qt_w) {                // wave-uniform: is my q-tile active?
            const int kv0 = t * 64;
            const char* lkc = (const char*)&lk[cur][0];
            const char* lvc = (const char*)&lv[cur][0];

            // S^T = K Q^T : s[sub][i] = S[k=kv0+sub*16+4g+i][q=wq0+l15]
            f32x4 s[4];
            __builtin_amdgcn_s_setprio(1);
#pragma unroll
            for (int sub = 0; sub < 4; sub++) {
                f32x4 a = fz;
#pragma unroll
                for (int ks = 0; ks < 4; ks++) {
                    int row = sub * 16 + l15;
                    int byte = (row * 256 + ks * 64 + g * 16) ^ ((row & 7) << 4);
                    s16x8 kf = *(const s16x8*)(lkc + byte);
                    a = mfma16(kf, qf[ks], a);
                }
                s[sub] = a;
            }
            __builtin_amdgcn_s_setprio(0);
            if (t == qt_w) {            // causal mask on diagonal supertile
#pragma unroll
                for (int sub = 0; sub < 4; sub++)
#pragma unroll
                    for (int i = 0; i < 4; i++) {
                        int k = kv0 + sub * 16 + 4 * g + i;
                        if (k > wq0 + l15) s[sub][i] = -1e30f;
                    }
            }
            // online softmax, lane-local q-row
            float m0 = s[0][0];
#pragma unroll
            for (int sub = 0; sub < 4; sub++)
#pragma unroll
                for (int i = 0; i < 4; i++) m0 = fmaxf(m0, s[sub][i]);
            m0 = fmaxf(m0, __shfl_xor(m0, 16));
            m0 = fmaxf(m0, __shfl_xor(m0, 32));
            float mnew = fmaxf(rmax, m0);
            float scal = __expf(rmax - mnew);
            rmax = mnew;
            float ls = 0.f;
#pragma unroll
            for (int sub = 0; sub < 4; sub++)
#pragma unroll
                for (int i = 0; i < 4; i++) {
                    float pv = __expf(s[sub][i] - mnew);
                    s[sub][i] = pv;
                    ls += pv;
                }
            ls += __shfl_xor(ls, 16);
            ls += __shfl_xor(ls, 32);
            rsum = rsum * scal + ls;
            // P -> bf16 -> LDS (one ds_write_b64 per sub)
#pragma unroll
            for (int sub = 0; sub < 4; sub++) {
                uint2 w01;
                w01.x = cvt_pk(s[sub][0], s[sub][1]);
                w01.y = cvt_pk(s[sub][2], s[sub][3]);
                int byte = (l15 * 128 + sub * 32 + g * 8) ^ ((l15 & 7) << 4);
                *(uint2*)((char*)lp + wid * 2048 + byte) = w01;
            }
#pragma unroll
            for (int n = 0; n < 8; n++)
#pragma unroll
                for (int i = 0; i < 4; i++) o[n][i] *= scal;
            // PV swapped: O^T += V^T (A, rows=d) x P^T (B, cols=q)
            __builtin_amdgcn_s_setprio(1);
#pragma unroll
            for (int ks2 = 0; ks2 < 2; ks2++) {
                int pbyte = (l15 * 128 + ks2 * 64 + g * 16) ^ ((l15 & 7) << 4);
                s16x8 pf = *(const s16x8*)((const char*)lp + wid * 2048 + pbyte);
#pragma unroll
                for (int n = 0; n < 8; n++) {
                    int vrow = n * 16 + l15;
                    int vbyte = (vrow * 128 + ks2 * 64 + g * 16) ^ ((vrow & 7) << 4);
                    s16x8 vf = *(const s16x8*)(lvc + vbyte);
                    o[n] = mfma16(vf, pf, o[n]);
                }
            }
            __builtin_amdgcn_s_setprio(0);
        }
        asm volatile("s_waitcnt vmcnt(0) lgkmcnt(0)" ::: "memory");
        __builtin_amdgcn_s_barrier();
        cur ^= 1;
    }
    float inv = 1.0f / rsum;
    float* orow = out + ((size_t)b * TT + wq0 + l15) * DD;
#pragma unroll
    for (int n = 0; n < 8; n++) {
        float4 r;
        r.x = o[n][0] * inv; r.y = o[n][1] * inv;
        r.z = o[n][2] * inv; r.w = o[n][3] * inv;
        *(float4*)(orow + n * 16 + 4 * g) = r;
    }
}

// ---------------- launch ---------------------------------------------------------
extern "C" void kernel_launch(void* const* d_in, const int* in_sizes, int n_in,
                              void* d_out, int out_size, void* d_ws, size_t ws_size,
                              hipStream_t stream) {
    const float* x  = (const float*)d_in[0];
    const float* wq = (const float*)d_in[1];
    const float* wk = (const float*)d_in[2];
    const float* wv = (const float*)d_in[3];
    float* out = (float*)d_out;
    char* ws = (char*)d_ws;
    short* wT = (short*)ws;
    short* qb = (short*)(ws + 786432);
    short* kb = (short*)(ws + 786432 + 8388608);
    short* vb = (short*)(ws + 786432 + 16777216);

    wt_kernel<<<1536, 256, 0, stream>>>(wq, wk, wv, wT);
    qkv_kernel<<<256, 512, 0, stream>>>(x, wT, qb, kb, vb);
    attn_kernel<<<256, 512, 0, stream>>>(qb, kb, vb, out);
}